// Round 21
// baseline (408.345 us; speedup 1.0000x reference)
//
#include <hip/hip_runtime.h>
#include <hip/hip_bf16.h>

#define DMODEL 2048
#define NHEADS 16
#define NKV 4
#define HD 128
#define SEQ 2048
#define BATCH 4

typedef __attribute__((ext_vector_type(2))) float f32x2;
typedef __attribute__((ext_vector_type(4))) float f32x4;
typedef __attribute__((ext_vector_type(16))) float f32x16;
typedef __attribute__((ext_vector_type(8))) short bf16x8;
typedef __attribute__((ext_vector_type(4))) unsigned int u32x4;

static __device__ __forceinline__ float bf2f(short u) {
    unsigned int x = ((unsigned int)(unsigned short)u) << 16;
    return __builtin_bit_cast(float, x);
}
static __device__ __forceinline__ short f2bf(float f) {
    unsigned int x = __builtin_bit_cast(unsigned int, f);
    unsigned int r = (x + 0x7fffu + ((x >> 16) & 1u)) >> 16;
    return (short)r;
}
static __device__ __forceinline__ unsigned int cvtpk_bf16(float lo, float hi) {
    unsigned int r;
    asm("v_cvt_pk_bf16_f32 %0, %1, %2" : "=v"(r) : "v"(lo), "v"(hi));
    return r;
}
// raw HW 2^x (v_exp_f32) - exp2f libm entry adds range-check VALU ops (R14 lesson)
static __device__ __forceinline__ float fexp2(float x) {
    float r;
    asm("v_exp_f32 %0, %1" : "=v"(r) : "v"(x));
    return r;
}
static __device__ __forceinline__ float ffract(float x) {
    float r;
    asm("v_fract_f32 %0, %1" : "=v"(r) : "v"(x));
    return r;
}
static __device__ __forceinline__ float fsin01(float x) {
    float r;
    asm("v_sin_f32 %0, %1" : "=v"(r) : "v"(x));
    return r;
}
static __device__ __forceinline__ float fcos01(float x) {
    float r;
    asm("v_cos_f32 %0, %1" : "=v"(r) : "v"(x));
    return r;
}
static __device__ __forceinline__ void gload16(const void* g, void* l) {
    __builtin_amdgcn_global_load_lds((const __attribute__((address_space(1))) void*)g,
                                     (__attribute__((address_space(3))) void*)l, 16, 0, 0);
}
static __device__ __forceinline__ void wbar6() {
    asm volatile("s_waitcnt vmcnt(6)" ::: "memory");
    __builtin_amdgcn_s_barrier();
    asm volatile("" ::: "memory");
}
static __device__ __forceinline__ void wbar4() {
    asm volatile("s_waitcnt vmcnt(4)" ::: "memory");
    __builtin_amdgcn_s_barrier();
    asm volatile("" ::: "memory");
}
// attn barriers: vmcnt(2) retires K(t+2) (leaves V(t+2) in flight) -- required
// because QK(t+1) is read one tile EARLY by the T15 pipeline.
static __device__ __forceinline__ void wbar2lg() {
    asm volatile("s_waitcnt vmcnt(2) lgkmcnt(0)" ::: "memory");
    __builtin_amdgcn_s_barrier();
    asm volatile("" ::: "memory");
}
static __device__ __forceinline__ void wbar0lg() {
    asm volatile("s_waitcnt vmcnt(0) lgkmcnt(0)" ::: "memory");
    __builtin_amdgcn_s_barrier();
    asm volatile("" ::: "memory");
}
static __device__ __forceinline__ void bar() {
    __builtin_amdgcn_s_barrier();
    asm volatile("" ::: "memory");
}

// ---- unified prep: conv_x (blocks 0..2047) + 4 weight transposes (2048..4607) ----
__global__ __launch_bounds__(256)
void prep(const float* __restrict__ x, short* __restrict__ xb,
          const float* __restrict__ Wq, const float* __restrict__ Wk,
          const float* __restrict__ Wv, const float* __restrict__ Wo,
          short* __restrict__ WqkvT, short* __restrict__ WoT) {
    __shared__ short Ts[64 * 72];
    const int bid = blockIdx.x, tid = threadIdx.x;

    if (bid < 2048) {
        const int n8 = BATCH * SEQ * DMODEL / 8;
        for (int i = bid * 256 + tid; i < n8; i += 2048 * 256) {
            float4 a = ((const float4*)x)[(size_t)i * 2];
            float4 b = ((const float4*)x)[(size_t)i * 2 + 1];
            bf16x8 o;
            o[0] = f2bf(a.x); o[1] = f2bf(a.y); o[2] = f2bf(a.z); o[3] = f2bf(a.w);
            o[4] = f2bf(b.x); o[5] = f2bf(b.y); o[6] = f2bf(b.z); o[7] = f2bf(b.w);
            ((bf16x8*)xb)[i] = o;
        }
        return;
    }

    const float* W;
    short* Wt;
    int C, r0, c0;
    if (bid < 3072) {
        int id = bid - 2048;
        W = Wq; Wt = WqkvT; C = 2048;
        c0 = (id & 31) * 64; r0 = (id >> 5) * 64;
    } else if (bid < 3328) {
        int id = bid - 3072;
        W = Wk; Wt = WqkvT + (size_t)2048 * 2048; C = 512;
        c0 = (id & 7) * 64; r0 = (id >> 3) * 64;
    } else if (bid < 3584) {
        int id = bid - 3328;
        W = Wv; Wt = WqkvT + (size_t)2560 * 2048; C = 512;
        c0 = (id & 7) * 64; r0 = (id >> 3) * 64;
    } else {
        int id = bid - 3584;
        W = Wo; Wt = WoT; C = 2048;
        c0 = (id & 31) * 64; r0 = (id >> 5) * 64;
    }
    const int R = 2048;
    for (int it = 0; it < 4; ++it) {
        int idx = it * 256 + tid;
        int row = idx >> 4, col4 = (idx & 15) * 4;
        float4 t = *(const float4*)&W[(size_t)(r0 + row) * C + c0 + col4];
        Ts[(col4 + 0) * 72 + row] = f2bf(t.x);
        Ts[(col4 + 1) * 72 + row] = f2bf(t.y);
        Ts[(col4 + 2) * 72 + row] = f2bf(t.z);
        Ts[(col4 + 3) * 72 + row] = f2bf(t.w);
    }
    __syncthreads();
    for (int it = 0; it < 2; ++it) {
        int idx = it * 256 + tid;
        int n = idx >> 3, k8 = (idx & 7) * 8;
        bf16x8 o = *(const bf16x8*)&Ts[n * 72 + k8];
        *(bf16x8*)&Wt[(size_t)(c0 + n) * R + r0 + k8] = o;
    }
}

// ------ 256x128 single-buffer 4-phase GEMM: C[M,N] = A[M,K] @ Bt[N,K]^T ------
// (R8: region-windowed staging, 3-phase prefetch age, 2 blocks/CU)
// launch_bounds(256,2): kernel needs ~120 VGPR; (256,3) caps at 84 -> spills
// (R19 regression). Do NOT raise the min-waves arg here.
// MODE: 0 = bf16 out, 1 = f32 out, 2 = QKV with fused RoPE on Q/K tiles.
template <int MODE>
__global__ __launch_bounds__(256, 2)
void gemm_sb(const short* __restrict__ A, const short* __restrict__ B,
             void* __restrict__ Cp, int M, int N, int K, int nbx) {
    __shared__ short As[256 * 64];
    __shared__ short Bs[128 * 64];
    const int tid = threadIdx.x, lane = tid & 63, w = tid >> 6;
    const int wr = w >> 1, wc = w & 1, lr = lane & 15, lg = lane >> 4;

    const int nwg = gridDim.x;
    const int qq = nwg >> 3, rr = nwg & 7;
    const int xcd = blockIdx.x & 7, loc = blockIdx.x >> 3;
    const int wg = (xcd < rr ? xcd * (qq + 1) : rr * (qq + 1) + (xcd - rr) * qq) + loc;
    const int m0 = (wg / nbx) * 256, n0 = (wg % nbx) * 128;

    const int srcchunk = ((lane & 7) ^ (lane >> 3)) * 8;
    const int lrow = w * 8;
    const int grow = w * 8 + (lane >> 3);

#define STG_A(T, HA)                                                              \
    {                                                                             \
        _Pragma("unroll") for (int i = 0; i < 4; ++i)                             \
            gload16(&A[(size_t)(m0 + (HA) * 128 + i * 32 + grow) * K +            \
                       (size_t)(T) * 64 + srcchunk],                              \
                    &As[((HA) * 128 + i * 32 + lrow) * 64]);                      \
    }
#define STG_B(T, HB)                                                              \
    {                                                                             \
        _Pragma("unroll") for (int i = 0; i < 2; ++i)                             \
            gload16(&B[(size_t)(n0 + (HB) * 64 + i * 32 + grow) * K +             \
                       (size_t)(T) * 64 + srcchunk],                              \
                    &Bs[((HB) * 64 + i * 32 + lrow) * 64]);                       \
    }

    f32x4 acc[2][4][2][2] = {};
    const int NT = K >> 6;

    STG_A(0, 0);
    STG_B(0, 0);
    STG_B(0, 1);
    STG_A(0, 1);

    bf16x8 af0[4][2], af1[4][2], bf0[2][2], bf1[2][2];
    for (int kt = 0; kt < NT; ++kt) {
        const int Tn = (kt + 1 < NT) ? kt + 1 : kt;

        wbar6();
#pragma unroll
        for (int q = 0; q < 4; ++q)
#pragma unroll
            for (int kk = 0; kk < 2; ++kk)
                af0[q][kk] = *(const bf16x8*)&As[(wr * 64 + q * 16 + lr) * 64 +
                                                 (((kk * 4 + lg) ^ (lr & 7)) << 3)];
#pragma unroll
        for (int r = 0; r < 2; ++r)
#pragma unroll
            for (int kk = 0; kk < 2; ++kk)
                bf0[r][kk] = *(const bf16x8*)&Bs[(wc * 32 + r * 16 + lr) * 64 +
                                                 (((kk * 4 + lg) ^ (lr & 7)) << 3)];
        __builtin_amdgcn_s_setprio(1);
#pragma unroll
        for (int q = 0; q < 4; ++q)
#pragma unroll
            for (int r = 0; r < 2; ++r)
#pragma unroll
                for (int kk = 0; kk < 2; ++kk)
                    acc[0][q][0][r] = __builtin_amdgcn_mfma_f32_16x16x32_bf16(
                        af0[q][kk], bf0[r][kk], acc[0][q][0][r], 0, 0, 0);
        __builtin_amdgcn_s_setprio(0);

        wbar4();
#pragma unroll
        for (int r = 0; r < 2; ++r)
#pragma unroll
            for (int kk = 0; kk < 2; ++kk)
                bf1[r][kk] = *(const bf16x8*)&Bs[(64 + wc * 32 + r * 16 + lr) * 64 +
                                                 (((kk * 4 + lg) ^ (lr & 7)) << 3)];
        STG_A(Tn, 0);
        STG_B(Tn, 0);
        __builtin_amdgcn_s_setprio(1);
#pragma unroll
        for (int q = 0; q < 4; ++q)
#pragma unroll
            for (int r = 0; r < 2; ++r)
#pragma unroll
                for (int kk = 0; kk < 2; ++kk)
                    acc[0][q][1][r] = __builtin_amdgcn_mfma_f32_16x16x32_bf16(
                        af0[q][kk], bf1[r][kk], acc[0][q][1][r], 0, 0, 0);
        __builtin_amdgcn_s_setprio(0);

        wbar6();
#pragma unroll
        for (int q = 0; q < 4; ++q)
#pragma unroll
            for (int kk = 0; kk < 2; ++kk)
                af1[q][kk] = *(const bf16x8*)&As[(128 + wr * 64 + q * 16 + lr) * 64 +
                                                 (((kk * 4 + lg) ^ (lr & 7)) << 3)];
        STG_B(Tn, 1);
        __builtin_amdgcn_s_setprio(1);
#pragma unroll
        for (int q = 0; q < 4; ++q)
#pragma unroll
            for (int r = 0; r < 2; ++r)
#pragma unroll
                for (int kk = 0; kk < 2; ++kk)
                    acc[1][q][0][r] = __builtin_amdgcn_mfma_f32_16x16x32_bf16(
                        af1[q][kk], bf0[r][kk], acc[1][q][0][r], 0, 0, 0);
        __builtin_amdgcn_s_setprio(0);

        bar();
        STG_A(Tn, 1);
        __builtin_amdgcn_s_setprio(1);
#pragma unroll
        for (int q = 0; q < 4; ++q)
#pragma unroll
            for (int r = 0; r < 2; ++r)
#pragma unroll
                for (int kk = 0; kk < 2; ++kk)
                    acc[1][q][1][r] = __builtin_amdgcn_mfma_f32_16x16x32_bf16(
                        af1[q][kk], bf1[r][kk], acc[1][q][1][r], 0, 0, 0);
        __builtin_amdgcn_s_setprio(0);
    }
    asm volatile("s_waitcnt vmcnt(0)" ::: "memory");

    if (MODE == 2 && n0 < 2560) {
        short* Cb = (short*)Cp;
        const float scl = (n0 >= 2048) ? 0.12751744695179782f : 1.0f;
        const float c13 = 13.287712379549449f / 64.0f;
        const float inv2pi = 0.15915494309189535f;
        float invf2[2];
#pragma unroll
        for (int r = 0; r < 2; ++r)
            invf2[r] = fexp2(-(float)(wc * 32 + r * 16 + lr) * c13) * inv2pi;
#pragma unroll
        for (int hA = 0; hA < 2; ++hA)
#pragma unroll
            for (int q = 0; q < 4; ++q)
#pragma unroll
                for (int r = 0; r < 2; ++r)
#pragma unroll
                    for (int j = 0; j < 4; ++j) {
                        int row = m0 + hA * 128 + wr * 64 + q * 16 + lg * 4 + j;
                        int pos = row & (SEQ - 1);
                        float fr = ffract((float)pos * invf2[r]);
                        float s = fsin01(fr), c = fcos01(fr);
                        float v0 = acc[hA][q][0][r][j];
                        float v1 = acc[hA][q][1][r][j];
                        int col0 = n0 + wc * 32 + r * 16 + lr;
                        Cb[(size_t)row * N + col0] = f2bf((v0 * c - v1 * s) * scl);
                        Cb[(size_t)row * N + col0 + 64] = f2bf((v1 * c + v0 * s) * scl);
                    }
    } else {
#pragma unroll
        for (int hA = 0; hA < 2; ++hA)
#pragma unroll
            for (int q = 0; q < 4; ++q)
#pragma unroll
                for (int hB = 0; hB < 2; ++hB)
#pragma unroll
                    for (int r = 0; r < 2; ++r)
#pragma unroll
                        for (int j = 0; j < 4; ++j) {
                            int row = m0 + hA * 128 + wr * 64 + q * 16 + lg * 4 + j;
                            int col = n0 + hB * 64 + wc * 32 + r * 16 + lr;
                            float v = acc[hA][q][hB][r][j];
                            if (MODE == 1) ((float*)Cp)[(size_t)row * N + col] = v;
                            else ((short*)Cp)[(size_t)row * N + col] = f2bf(v);
                        }
    }
#undef STG_A
#undef STG_B
}

// ---------------- fallback GEMM (round-1): f32 inputs, convert in-kernel ----------------
template <bool A_F32, bool C_F32>
__global__ __launch_bounds__(256)
void gemm_kernel(const void* __restrict__ Ap, const float* __restrict__ Bp,
                 void* __restrict__ Cp, int M, int N, int K) {
    const int BK = 32, PAD = 8, LDT = BK + PAD;
    __shared__ short As[128 * LDT];
    __shared__ short Bt[128 * LDT];
    const int tid = threadIdx.x;
    const int lane = tid & 63, w = tid >> 6;
    const int wr = w >> 1, wc = w & 1;
    const int lr = lane & 15, lg = lane >> 4;
    const int m0 = blockIdx.y * 128, n0 = blockIdx.x * 128;
    f32x4 acc[4][4] = {};

    for (int k0 = 0; k0 < K; k0 += BK) {
        __syncthreads();
        for (int it = 0; it < 4; ++it) {
            int row = (tid >> 3) + it * 32;
            int kk = (tid & 7) * 4;
            short4 o;
            if (A_F32) {
                const float* A = (const float*)Ap;
                float4 t = *(const float4*)&A[(size_t)(m0 + row) * K + k0 + kk];
                o.x = f2bf(t.x); o.y = f2bf(t.y); o.z = f2bf(t.z); o.w = f2bf(t.w);
            } else {
                const short* A = (const short*)Ap;
                o = *(const short4*)&A[(size_t)(m0 + row) * K + k0 + kk];
            }
            *(short4*)&As[row * LDT + kk] = o;
        }
        for (int it = 0; it < 4; ++it) {
            int krow = (tid >> 5) + it * 8;
            int col = (tid & 31) * 4;
            float4 t = *(const float4*)&Bp[(size_t)(k0 + krow) * N + n0 + col];
            Bt[(col + 0) * LDT + krow] = f2bf(t.x);
            Bt[(col + 1) * LDT + krow] = f2bf(t.y);
            Bt[(col + 2) * LDT + krow] = f2bf(t.z);
            Bt[(col + 3) * LDT + krow] = f2bf(t.w);
        }
        __syncthreads();
        bf16x8 af[4], bfr[4];
        for (int rb = 0; rb < 4; ++rb)
            af[rb] = *(const bf16x8*)&As[(wr * 64 + rb * 16 + lr) * LDT + lg * 8];
        for (int cb = 0; cb < 4; ++cb)
            bfr[cb] = *(const bf16x8*)&Bt[(wc * 64 + cb * 16 + lr) * LDT + lg * 8];
        for (int rb = 0; rb < 4; ++rb)
            for (int cb = 0; cb < 4; ++cb)
                acc[rb][cb] = __builtin_amdgcn_mfma_f32_16x16x32_bf16(
                    af[rb], bfr[cb], acc[rb][cb], 0, 0, 0);
    }

    for (int rb = 0; rb < 4; ++rb)
        for (int cb = 0; cb < 4; ++cb)
            for (int j = 0; j < 4; ++j) {
                int row = m0 + wr * 64 + rb * 16 + lg * 4 + j;
                int col = n0 + wc * 64 + cb * 16 + lr;
                float v = acc[rb][cb][j];
                if (C_F32) ((float*)Cp)[(size_t)row * N + col] = v;
                else ((short*)Cp)[(size_t)row * N + col] = f2bf(v);
            }
}

// ------- RoPE in-place (fallback path only); K pre-scaled log2(e)/sqrt(hd) -------
__global__ __launch_bounds__(256)
void rope_kernel(short* __restrict__ Qp, int ldq, short* __restrict__ Kp, int ldk) {
    const int QP = BATCH * SEQ * NHEADS * 64;
    const int KP = BATCH * SEQ * NKV * 64;
    const int total = QP + KP;
    const float kscale = 0.12751744695179782f;
    for (int idx = blockIdx.x * blockDim.x + threadIdx.x; idx < total;
         idx += gridDim.x * blockDim.x) {
        short* base;
        size_t off;
        int i, row;
        float scl;
        if (idx < QP) {
            i = idx & 63;
            int hh = (idx >> 6) & (NHEADS - 1);
            row = idx >> 10;
            base = Qp;
            off = (size_t)row * ldq + hh * HD;
            scl = 1.0f;
        } else {
            int t = idx - QP;
            i = t & 63;
            int hh = (t >> 6) & (NKV - 1);
            row = t >> 8;
            base = Kp;
            off = (size_t)row * ldk + hh * HD;
            scl = kscale;
        }
        int pos = row & (SEQ - 1);
        float invf = exp2f(-(float)i * (13.287712379549449f / 64.0f));
        float ang = (float)pos * invf;
        float s, c;
        sincosf(ang, &s, &c);
        float t1 = bf2f(base[off + i]);
        float t2 = bf2f(base[off + i + 64]);
        base[off + i] = f2bf((t1 * c - t2 * s) * scl);
        base[off + i + 64] = f2bf((t2 * c + t1 * s) * scl);
    }
}

// ---- Flash attention: 8 waves, QBLK=256, 32x32 MFMA, in-register P ----
// R20 structure + T15 cross-tile pipeline: QK(t+1) MFMAs issue BEFORE
// softmax(t), so softmax VALU/trans overlaps the next tile's matrix work.
// Requires K(t+1) landed by barrier(t-1): end-of-tile wait is vmcnt(2)
// (retires K(t+2), leaves V(t+2) in flight). Static sA/sB double state,
// manually unrolled 2-tile loop (ntiles always even).
__global__ __launch_bounds__(512, 2)
void attn_kernel(const short* __restrict__ Qp, int ldq,
                 const short* __restrict__ Kp, int ldk,
                 const short* __restrict__ Vp, int ldv,
                 short* __restrict__ O) {
    __shared__ short Ks[3][64 * 128];
    __shared__ short Vt[2][128 * 64];

    const int tid = threadIdx.x, lane = tid & 63, w = tid >> 6;
    const int l31 = lane & 31, lh = lane >> 5, l7 = lane & 7;
    const int hq = blockIdx.y, b = blockIdx.z;
    const int kvh = hq >> 2;
    const size_t brow = (size_t)b * SEQ;

    const int d0 = (tid & 15) * 8;
    const int rvb = (tid >> 4) * 2;   // 0..62 even
    bf16x8 vreg[2];

#define STAGE_K(T, BUF)                                                              \
    {                                                                                \
        _Pragma("unroll") for (int it = 0; it < 2; ++it) {                           \
            int row = w * 8 + it * 4 + (lane >> 4);                                  \
            int cblk = (lane & 15) ^ (row & 7);                                      \
            gload16(&Kp[(brow + (size_t)(T) * 64 + row) * ldk + kvh * HD + cblk * 8],\
                    &Ks[BUF][(w * 8 + it * 4) * 128]);                               \
        }                                                                            \
    }
#define LOAD_V(T)                                                                    \
    {                                                                                \
        _Pragma("unroll") for (int h2 = 0; h2 < 2; ++h2)                             \
            vreg[h2] = *(const bf16x8*)&Vp[(brow + (size_t)(T) * 64 + rvb + h2) *    \
                                           ldv + kvh * HD + d0];                     \
    }
#define WRITE_V(BUF)                                                                 \
    {                                                                                \
        _Pragma("unroll") for (int e = 0; e < 8; ++e) {                              \
            int dd = d0 + e;                                                         \
            int gg = (e ^ (tid & 15)) & 7;                                           \
            unsigned int pk = ((unsigned int)(unsigned short)vreg[0][e]) |           \
                              (((unsigned int)(unsigned short)vreg[1][e]) << 16);    \
            *(unsigned int*)&Vt[BUF][dd * 64 + (((rvb >> 3) ^ gg) << 3) + (rvb & 7)] = pk;\
        }                                                                            \
    }
#define QK_ISSUE(SDST, KBUF)                                                         \
    {                                                                                \
        SDST[0] = (f32x16){};                                                        \
        SDST[1] = (f32x16){};                                                        \
        __builtin_amdgcn_s_setprio(1);                                               \
        _Pragma("unroll") for (int kvb = 0; kvb < 2; ++kvb) {                        \
            const int kvrow = kvb * 32 + l31;                                        \
            _Pragma("unroll") for (int kc = 0; kc < 8; ++kc) {                       \
                int c = kc * 2 + lh;                                                 \
                int cp = (c & 8) | ((c ^ l7) & 7);                                   \
                bf16x8 kf = *(const bf16x8*)&Ks[KBUF][kvrow * 128 + cp * 8];         \
                SDST[kvb] = __builtin_amdgcn_mfma_f32_32x32x16_bf16(                 \
                    kf, qf[kc], SDST[kvb], 0, 0, 0);                                 \
            }                                                                        \
        }                                                                            \
        __builtin_amdgcn_s_setprio(0);                                               \
    }
// one tile: softmax+PV on SCUR (tile T), QK(t+1) into SNEXT issued first
#define TILE_BODY(T, SCUR, SNEXT)                                                    \
    {                                                                                \
        const int nxt = cur ^ 1;                                                     \
        const bool pre = ((T) + 1 < ntiles);                                         \
        const bool deep = ((T) + 2 < ntiles);                                        \
        const int kb2 = (kcur >= 1) ? kcur - 1 : kcur + 2;                           \
        const int knx = (kcur < 2) ? kcur + 1 : 0;                                   \
        if (deep) { STAGE_K((T) + 2, kb2); }                                         \
        if (pre) { QK_ISSUE(SNEXT, knx); }                                           \
        const int kv0 = (T) * 64;                                                    \
        float st[32];                                                                \
        const bool need_mask = (kv0 + 63 > qrow);                                    \
        _Pragma("unroll") for (int kvb = 0; kvb < 2; ++kvb)                          \
            _Pragma("unroll") for (int r = 0; r < 16; ++r) {                         \
                float s = SCUR[kvb][r];                                              \
                if (need_mask) {                                                     \
                    int kvloc = kvb * 32 + (r & 3) + 8 * (r >> 2) + 4 * lh;          \
                    if (kv0 + kvloc > qrow) s = -__builtin_inff();                   \
                }                                                                    \
                st[kvb * 16 + r] = s;                                                \
            }                                                                        \
        f32x2 p2[16];                                                                \
        _Pragma("unroll") for (int i = 0; i < 16; ++i)                               \
            p2[i] = (f32x2){st[2 * i], st[2 * i + 1]};                               \
        f32x2 x8[8], x4[4], x2v[2], x1;                                              \
        _Pragma("unroll") for (int i = 0; i < 8; ++i)                                \
            x8[i] = __builtin_elementwise_max(p2[i], p2[i + 8]);                     \
        _Pragma("unroll") for (int i = 0; i < 4; ++i)                                \
            x4[i] = __builtin_elementwise_max(x8[i], x8[i + 4]);                     \
        x2v[0] = __builtin_elementwise_max(x4[0], x4[2]);                            \
        x2v[1] = __builtin_elementwise_max(x4[1], x4[3]);                            \
        x1 = __builtin_elementwise_max(x2v[0], x2v[1]);                              \
        float rowmax = fmaxf(x1[0], x1[1]);                                          \
        rowmax = fmaxf(rowmax, __shfl_xor(rowmax, 32, 64));                          \
        if (!__all(rowmax <= mrun + 11.54f)) {                                       \
            float mnew = fmaxf(mrun, rowmax);                                        \
            float alpha = fexp2(mrun - mnew);                                        \
            lrun *= alpha;                                                           \
            _Pragma("unroll") for (int db = 0; db < 4; ++db)                         \
                _Pragma("unroll") for (int r = 0; r < 16; ++r) oacc[db][r] *= alpha; \
            mrun = mnew;                                                             \
        }                                                                            \
        const f32x2 mr2 = (f32x2){mrun, mrun};                                       \
        _Pragma("unroll") for (int i = 0; i < 16; ++i) {                             \
            f32x2 dd2 = p2[i] - mr2;                                                 \
            st[2 * i] = fexp2(dd2[0]);                                               \
            st[2 * i + 1] = fexp2(dd2[1]);                                           \
        }                                                                            \
        f32x2 q2[16];                                                                \
        _Pragma("unroll") for (int i = 0; i < 16; ++i)                               \
            q2[i] = (f32x2){st[2 * i], st[2 * i + 1]};                               \
        f32x2 t8[8], t4[4], t2v[2], t1;                                              \
        _Pragma("unroll") for (int i = 0; i < 8; ++i) t8[i] = q2[i] + q2[i + 8];     \
        _Pragma("unroll") for (int i = 0; i < 4; ++i) t4[i] = t8[i] + t8[i + 4];     \
        t2v[0] = t4[0] + t4[2];                                                      \
        t2v[1] = t4[1] + t4[3];                                                      \
        t1 = t2v[0] + t2v[1];                                                        \
        float rs = t1[0] + t1[1];                                                    \
        rs += __shfl_xor(rs, 32, 64);                                                \
        lrun += rs;                                                                  \
        if (pre) {                                                                   \
            WRITE_V(nxt);                                                            \
            if (deep) { LOAD_V((T) + 2); }                                           \
        }                                                                            \
        u32x4 pfrag[4];                                                              \
        _Pragma("unroll") for (int kvc = 0; kvc < 4; ++kvc) {                        \
            int base2 = (kvc >> 1) * 16 + (kvc & 1) * 8;                             \
            unsigned int lo0 = cvtpk_bf16(st[base2 + 0], st[base2 + 1]);             \
            unsigned int lo1 = cvtpk_bf16(st[base2 + 2], st[base2 + 3]);             \
            unsigned int hi0 = cvtpk_bf16(st[base2 + 4], st[base2 + 5]);             \
            unsigned int hi1 = cvtpk_bf16(st[base2 + 6], st[base2 + 7]);             \
            unsigned int rlo0 = __shfl_xor(lo0, 32, 64);                             \
            unsigned int rlo1 = __shfl_xor(lo1, 32, 64);                             \
            unsigned int rhi0 = __shfl_xor(hi0, 32, 64);                             \
            unsigned int rhi1 = __shfl_xor(hi1, 32, 64);                             \
            u32x4 pu;                                                                \
            pu[0] = lh ? rhi0 : lo0;                                                 \
            pu[1] = lh ? rhi1 : lo1;                                                 \
            pu[2] = lh ? hi0 : rlo0;                                                 \
            pu[3] = lh ? hi1 : rlo1;                                                 \
            pfrag[kvc] = pu;                                                         \
        }                                                                            \
        __builtin_amdgcn_s_setprio(1);                                               \
        _Pragma("unroll") for (int db = 0; db < 4; ++db) {                           \
            const int d = db * 32 + l31;                                             \
            const int g = (d ^ (d >> 3)) & 7;                                        \
            _Pragma("unroll") for (int kvc = 0; kvc < 4; ++kvc) {                    \
                int cp = ((kvc * 2 + lh) ^ g) & 7;                                   \
                bf16x8 vf = *(const bf16x8*)&Vt[cur][d * 64 + cp * 8];               \
                oacc[db] = __builtin_amdgcn_mfma_f32_32x32x16_bf16(                  \
                    vf, __builtin_bit_cast(bf16x8, pfrag[kvc]), oacc[db], 0, 0, 0);  \
            }                                                                        \
        }                                                                            \
        __builtin_amdgcn_s_setprio(0);                                               \
        if (pre) {                                                                   \
            if (deep) { wbar2lg(); } else { wbar0lg(); }                             \
            cur = nxt;                                                               \
            kcur = knx;                                                              \
        }                                                                            \
    }

    for (int pass = 0; pass < 2; ++pass) {
        const int qt = (pass == 0) ? (int)blockIdx.x : 7 - (int)blockIdx.x;
        const int q0 = qt * 256;
        const int qrow = q0 + w * 32 + l31;

        bf16x8 qf[8];
#pragma unroll
        for (int kc = 0; kc < 8; ++kc)
            qf[kc] = *(const bf16x8*)&Qp[(brow + qrow) * ldq + hq * HD +
                                         kc * 16 + lh * 8];

        f32x16 oacc[4] = {};
        float mrun = -__builtin_inff(), lrun = 0.f;

        const int ntiles = 4 * qt + 4;  // >= 4, always even

        __syncthreads();                // pass boundary: prev readers done
        STAGE_K(0, 0);
        LOAD_V(0);
        __syncthreads();                // K0 landed (syncthreads drains vmcnt)
        WRITE_V(0);
        STAGE_K(1, 1);
        LOAD_V(1);
        __syncthreads();                // K1 landed; Vt[0] visible

        int cur = 0;
        int kcur = 0;
        f32x16 sA[2], sB[2];
        QK_ISSUE(sA, 0);                // tile 0 scores ahead of the loop

        for (int t = 0; t < ntiles; t += 2) {
            TILE_BODY(t, sA, sB);
            TILE_BODY(t + 1, sB, sA);
        }

        const float invl = 1.0f / lrun;
#pragma unroll
        for (int db = 0; db < 4; ++db)
#pragma unroll
            for (int j = 0; j < 4; ++j) {
                short4 o4;
                o4.x = f2bf(oacc[db][j * 4 + 0] * invl);
                o4.y = f2bf(oacc[db][j * 4 + 1] * invl);
                o4.z = f2bf(oacc[db][j * 4 + 2] * invl);
                o4.w = f2bf(oacc[db][j * 4 + 3] * invl);
                *(short4*)&O[(brow + qrow) * DMODEL + hq * HD +
                             db * 32 + 8 * j + 4 * lh] = o4;
            }
    }
#undef STAGE_K
#undef LOAD_V
#undef WRITE_V
#undef QK_ISSUE
#undef TILE_BODY
}

extern "C" void kernel_launch(void* const* d_in, const int* in_sizes, int n_in,
                              void* d_out, int out_size, void* d_ws, size_t ws_size,
                              hipStream_t stream) {
    const float* x = (const float*)d_in[0];
    const float* Wq = (const float*)d_in[1];
    const float* Wk = (const float*)d_in[2];
    const float* Wv = (const float*)d_in[3];
    const float* Wo = (const float*)d_in[4];
    float* out = (float*)d_out;

    const size_t BS = (size_t)BATCH * SEQ;  // 8192
    dim3 blk(256);

    const size_t planA_shorts = BS * 2048 + BS * 3072 + (size_t)3072 * 2048 + (size_t)2048 * 2048;
    if (ws_size >= planA_shorts * 2) {
        short* xb = (short*)d_ws;                    // [8192][2048] bf16 (reused as AO)
        short* QKV = xb + BS * 2048;                 // [8192][3072]: Q | K | V
        short* WqkvT = QKV + BS * 3072;              // [3072][2048]
        short* WoT = WqkvT + (size_t)3072 * 2048;    // [2048][2048]
        short* AO = xb;

        prep<<<dim3(4608), blk, 0, stream>>>(x, xb, Wq, Wk, Wv, Wo, WqkvT, WoT);
        gemm_sb<2><<<dim3(768), blk, 0, stream>>>(xb, WqkvT, (void*)QKV,
                                                  8192, 3072, 2048, 24);
        attn_kernel<<<dim3(4, NHEADS, BATCH), dim3(512), 0, stream>>>(
            QKV, 3072, QKV + 2048, 3072, QKV + 2560, 3072, AO);
        gemm_sb<1><<<dim3(512), blk, 0, stream>>>(AO, WoT, (void*)out,
                                                  8192, 2048, 2048, 16);
    } else {
        short* Qb = (short*)d_ws;
        short* Kb = Qb + BS * DMODEL;
        short* Vb = Kb + BS * (NKV * HD);
        short* AO = Vb + BS * (NKV * HD);
        gemm_kernel<true, false><<<dim3(16, 64), blk, 0, stream>>>((const void*)x, Wq, (void*)Qb, 8192, 2048, 2048);
        gemm_kernel<true, false><<<dim3(4, 64), blk, 0, stream>>>((const void*)x, Wk, (void*)Kb, 8192, 512, 2048);
        gemm_kernel<true, false><<<dim3(4, 64), blk, 0, stream>>>((const void*)x, Wv, (void*)Vb, 8192, 512, 2048);
        rope_kernel<<<dim3(4096), blk, 0, stream>>>(Qb, 2048, Kb, 512);
        attn_kernel<<<dim3(4, NHEADS, BATCH), dim3(512), 0, stream>>>(
            Qb, 2048, Kb, 512, Vb, 512, AO);
        gemm_kernel<false, true><<<dim3(16, 64), blk, 0, stream>>>((const void*)AO, Wo, (void*)out, 8192, 2048, 2048);
    }
}

// Round 22
// 321.804 us; speedup vs baseline: 1.2689x; 1.2689x over previous
//
#include <hip/hip_runtime.h>
#include <hip/hip_bf16.h>

#define DMODEL 2048
#define NHEADS 16
#define NKV 4
#define HD 128
#define SEQ 2048
#define BATCH 4

typedef __attribute__((ext_vector_type(2))) float f32x2;
typedef __attribute__((ext_vector_type(4))) float f32x4;
typedef __attribute__((ext_vector_type(16))) float f32x16;
typedef __attribute__((ext_vector_type(8))) short bf16x8;
typedef __attribute__((ext_vector_type(4))) unsigned int u32x4;

static __device__ __forceinline__ float bf2f(short u) {
    unsigned int x = ((unsigned int)(unsigned short)u) << 16;
    return __builtin_bit_cast(float, x);
}
static __device__ __forceinline__ short f2bf(float f) {
    unsigned int x = __builtin_bit_cast(unsigned int, f);
    unsigned int r = (x + 0x7fffu + ((x >> 16) & 1u)) >> 16;
    return (short)r;
}
static __device__ __forceinline__ unsigned int cvtpk_bf16(float lo, float hi) {
    unsigned int r;
    asm("v_cvt_pk_bf16_f32 %0, %1, %2" : "=v"(r) : "v"(lo), "v"(hi));
    return r;
}
// raw HW 2^x (v_exp_f32) - exp2f libm entry adds range-check VALU ops (R14 lesson)
static __device__ __forceinline__ float fexp2(float x) {
    float r;
    asm("v_exp_f32 %0, %1" : "=v"(r) : "v"(x));
    return r;
}
static __device__ __forceinline__ float ffract(float x) {
    float r;
    asm("v_fract_f32 %0, %1" : "=v"(r) : "v"(x));
    return r;
}
static __device__ __forceinline__ float fsin01(float x) {
    float r;
    asm("v_sin_f32 %0, %1" : "=v"(r) : "v"(x));
    return r;
}
static __device__ __forceinline__ float fcos01(float x) {
    float r;
    asm("v_cos_f32 %0, %1" : "=v"(r) : "v"(x));
    return r;
}
static __device__ __forceinline__ void gload16(const void* g, void* l) {
    __builtin_amdgcn_global_load_lds((const __attribute__((address_space(1))) void*)g,
                                     (__attribute__((address_space(3))) void*)l, 16, 0, 0);
}
static __device__ __forceinline__ void wbar6() {
    asm volatile("s_waitcnt vmcnt(6)" ::: "memory");
    __builtin_amdgcn_s_barrier();
    asm volatile("" ::: "memory");
}
static __device__ __forceinline__ void wbar4() {
    asm volatile("s_waitcnt vmcnt(4)" ::: "memory");
    __builtin_amdgcn_s_barrier();
    asm volatile("" ::: "memory");
}
static __device__ __forceinline__ void wbar6lg() {
    asm volatile("s_waitcnt vmcnt(6) lgkmcnt(0)" ::: "memory");
    __builtin_amdgcn_s_barrier();
    asm volatile("" ::: "memory");
}
static __device__ __forceinline__ void wbar0lg() {
    asm volatile("s_waitcnt vmcnt(0) lgkmcnt(0)" ::: "memory");
    __builtin_amdgcn_s_barrier();
    asm volatile("" ::: "memory");
}
static __device__ __forceinline__ void bar() {
    __builtin_amdgcn_s_barrier();
    asm volatile("" ::: "memory");
}

// ---- unified prep: conv_x (blocks 0..2047) + 4 weight transposes (2048..4607) ----
__global__ __launch_bounds__(256)
void prep(const float* __restrict__ x, short* __restrict__ xb,
          const float* __restrict__ Wq, const float* __restrict__ Wk,
          const float* __restrict__ Wv, const float* __restrict__ Wo,
          short* __restrict__ WqkvT, short* __restrict__ WoT) {
    __shared__ short Ts[64 * 72];
    const int bid = blockIdx.x, tid = threadIdx.x;

    if (bid < 2048) {
        const int n8 = BATCH * SEQ * DMODEL / 8;
        for (int i = bid * 256 + tid; i < n8; i += 2048 * 256) {
            float4 a = ((const float4*)x)[(size_t)i * 2];
            float4 b = ((const float4*)x)[(size_t)i * 2 + 1];
            bf16x8 o;
            o[0] = f2bf(a.x); o[1] = f2bf(a.y); o[2] = f2bf(a.z); o[3] = f2bf(a.w);
            o[4] = f2bf(b.x); o[5] = f2bf(b.y); o[6] = f2bf(b.z); o[7] = f2bf(b.w);
            ((bf16x8*)xb)[i] = o;
        }
        return;
    }

    const float* W;
    short* Wt;
    int C, r0, c0;
    if (bid < 3072) {
        int id = bid - 2048;
        W = Wq; Wt = WqkvT; C = 2048;
        c0 = (id & 31) * 64; r0 = (id >> 5) * 64;
    } else if (bid < 3328) {
        int id = bid - 3072;
        W = Wk; Wt = WqkvT + (size_t)2048 * 2048; C = 512;
        c0 = (id & 7) * 64; r0 = (id >> 3) * 64;
    } else if (bid < 3584) {
        int id = bid - 3328;
        W = Wv; Wt = WqkvT + (size_t)2560 * 2048; C = 512;
        c0 = (id & 7) * 64; r0 = (id >> 3) * 64;
    } else {
        int id = bid - 3584;
        W = Wo; Wt = WoT; C = 2048;
        c0 = (id & 31) * 64; r0 = (id >> 5) * 64;
    }
    const int R = 2048;
    for (int it = 0; it < 4; ++it) {
        int idx = it * 256 + tid;
        int row = idx >> 4, col4 = (idx & 15) * 4;
        float4 t = *(const float4*)&W[(size_t)(r0 + row) * C + c0 + col4];
        Ts[(col4 + 0) * 72 + row] = f2bf(t.x);
        Ts[(col4 + 1) * 72 + row] = f2bf(t.y);
        Ts[(col4 + 2) * 72 + row] = f2bf(t.z);
        Ts[(col4 + 3) * 72 + row] = f2bf(t.w);
    }
    __syncthreads();
    for (int it = 0; it < 2; ++it) {
        int idx = it * 256 + tid;
        int n = idx >> 3, k8 = (idx & 7) * 8;
        bf16x8 o = *(const bf16x8*)&Ts[n * 72 + k8];
        *(bf16x8*)&Wt[(size_t)(c0 + n) * R + r0 + k8] = o;
    }
}

// ------ 256x128 single-buffer 4-phase GEMM: C[M,N] = A[M,K] @ Bt[N,K]^T ------
// (R8: region-windowed staging, 3-phase prefetch age, 2 blocks/CU)
// launch_bounds(256,2): kernel needs ~120 VGPR; (256,3) caps at 84 -> spills
// (R19 regression). Do NOT raise the min-waves arg here.
// MODE: 0 = bf16 out, 1 = f32 out, 2 = QKV with fused RoPE on Q/K tiles.
template <int MODE>
__global__ __launch_bounds__(256, 2)
void gemm_sb(const short* __restrict__ A, const short* __restrict__ B,
             void* __restrict__ Cp, int M, int N, int K, int nbx) {
    __shared__ short As[256 * 64];
    __shared__ short Bs[128 * 64];
    const int tid = threadIdx.x, lane = tid & 63, w = tid >> 6;
    const int wr = w >> 1, wc = w & 1, lr = lane & 15, lg = lane >> 4;

    const int nwg = gridDim.x;
    const int qq = nwg >> 3, rr = nwg & 7;
    const int xcd = blockIdx.x & 7, loc = blockIdx.x >> 3;
    const int wg = (xcd < rr ? xcd * (qq + 1) : rr * (qq + 1) + (xcd - rr) * qq) + loc;
    const int m0 = (wg / nbx) * 256, n0 = (wg % nbx) * 128;

    const int srcchunk = ((lane & 7) ^ (lane >> 3)) * 8;
    const int lrow = w * 8;
    const int grow = w * 8 + (lane >> 3);

#define STG_A(T, HA)                                                              \
    {                                                                             \
        _Pragma("unroll") for (int i = 0; i < 4; ++i)                             \
            gload16(&A[(size_t)(m0 + (HA) * 128 + i * 32 + grow) * K +            \
                       (size_t)(T) * 64 + srcchunk],                              \
                    &As[((HA) * 128 + i * 32 + lrow) * 64]);                      \
    }
#define STG_B(T, HB)                                                              \
    {                                                                             \
        _Pragma("unroll") for (int i = 0; i < 2; ++i)                             \
            gload16(&B[(size_t)(n0 + (HB) * 64 + i * 32 + grow) * K +             \
                       (size_t)(T) * 64 + srcchunk],                              \
                    &Bs[((HB) * 64 + i * 32 + lrow) * 64]);                       \
    }

    f32x4 acc[2][4][2][2] = {};
    const int NT = K >> 6;

    STG_A(0, 0);
    STG_B(0, 0);
    STG_B(0, 1);
    STG_A(0, 1);

    bf16x8 af0[4][2], af1[4][2], bf0[2][2], bf1[2][2];
    for (int kt = 0; kt < NT; ++kt) {
        const int Tn = (kt + 1 < NT) ? kt + 1 : kt;

        wbar6();
#pragma unroll
        for (int q = 0; q < 4; ++q)
#pragma unroll
            for (int kk = 0; kk < 2; ++kk)
                af0[q][kk] = *(const bf16x8*)&As[(wr * 64 + q * 16 + lr) * 64 +
                                                 (((kk * 4 + lg) ^ (lr & 7)) << 3)];
#pragma unroll
        for (int r = 0; r < 2; ++r)
#pragma unroll
            for (int kk = 0; kk < 2; ++kk)
                bf0[r][kk] = *(const bf16x8*)&Bs[(wc * 32 + r * 16 + lr) * 64 +
                                                 (((kk * 4 + lg) ^ (lr & 7)) << 3)];
        __builtin_amdgcn_s_setprio(1);
#pragma unroll
        for (int q = 0; q < 4; ++q)
#pragma unroll
            for (int r = 0; r < 2; ++r)
#pragma unroll
                for (int kk = 0; kk < 2; ++kk)
                    acc[0][q][0][r] = __builtin_amdgcn_mfma_f32_16x16x32_bf16(
                        af0[q][kk], bf0[r][kk], acc[0][q][0][r], 0, 0, 0);
        __builtin_amdgcn_s_setprio(0);

        wbar4();
#pragma unroll
        for (int r = 0; r < 2; ++r)
#pragma unroll
            for (int kk = 0; kk < 2; ++kk)
                bf1[r][kk] = *(const bf16x8*)&Bs[(64 + wc * 32 + r * 16 + lr) * 64 +
                                                 (((kk * 4 + lg) ^ (lr & 7)) << 3)];
        STG_A(Tn, 0);
        STG_B(Tn, 0);
        __builtin_amdgcn_s_setprio(1);
#pragma unroll
        for (int q = 0; q < 4; ++q)
#pragma unroll
            for (int r = 0; r < 2; ++r)
#pragma unroll
                for (int kk = 0; kk < 2; ++kk)
                    acc[0][q][1][r] = __builtin_amdgcn_mfma_f32_16x16x32_bf16(
                        af0[q][kk], bf1[r][kk], acc[0][q][1][r], 0, 0, 0);
        __builtin_amdgcn_s_setprio(0);

        wbar6();
#pragma unroll
        for (int q = 0; q < 4; ++q)
#pragma unroll
            for (int kk = 0; kk < 2; ++kk)
                af1[q][kk] = *(const bf16x8*)&As[(128 + wr * 64 + q * 16 + lr) * 64 +
                                                 (((kk * 4 + lg) ^ (lr & 7)) << 3)];
        STG_B(Tn, 1);
        __builtin_amdgcn_s_setprio(1);
#pragma unroll
        for (int q = 0; q < 4; ++q)
#pragma unroll
            for (int r = 0; r < 2; ++r)
#pragma unroll
                for (int kk = 0; kk < 2; ++kk)
                    acc[1][q][0][r] = __builtin_amdgcn_mfma_f32_16x16x32_bf16(
                        af1[q][kk], bf0[r][kk], acc[1][q][0][r], 0, 0, 0);
        __builtin_amdgcn_s_setprio(0);

        bar();
        STG_A(Tn, 1);
        __builtin_amdgcn_s_setprio(1);
#pragma unroll
        for (int q = 0; q < 4; ++q)
#pragma unroll
            for (int r = 0; r < 2; ++r)
#pragma unroll
                for (int kk = 0; kk < 2; ++kk)
                    acc[1][q][1][r] = __builtin_amdgcn_mfma_f32_16x16x32_bf16(
                        af1[q][kk], bf1[r][kk], acc[1][q][1][r], 0, 0, 0);
        __builtin_amdgcn_s_setprio(0);
    }
    asm volatile("s_waitcnt vmcnt(0)" ::: "memory");

    if (MODE == 2 && n0 < 2560) {
        short* Cb = (short*)Cp;
        const float scl = (n0 >= 2048) ? 0.12751744695179782f : 1.0f;
        const float c13 = 13.287712379549449f / 64.0f;
        const float inv2pi = 0.15915494309189535f;
        float invf2[2];
#pragma unroll
        for (int r = 0; r < 2; ++r)
            invf2[r] = fexp2(-(float)(wc * 32 + r * 16 + lr) * c13) * inv2pi;
#pragma unroll
        for (int hA = 0; hA < 2; ++hA)
#pragma unroll
            for (int q = 0; q < 4; ++q)
#pragma unroll
                for (int r = 0; r < 2; ++r)
#pragma unroll
                    for (int j = 0; j < 4; ++j) {
                        int row = m0 + hA * 128 + wr * 64 + q * 16 + lg * 4 + j;
                        int pos = row & (SEQ - 1);
                        float fr = ffract((float)pos * invf2[r]);
                        float s = fsin01(fr), c = fcos01(fr);
                        float v0 = acc[hA][q][0][r][j];
                        float v1 = acc[hA][q][1][r][j];
                        int col0 = n0 + wc * 32 + r * 16 + lr;
                        Cb[(size_t)row * N + col0] = f2bf((v0 * c - v1 * s) * scl);
                        Cb[(size_t)row * N + col0 + 64] = f2bf((v1 * c + v0 * s) * scl);
                    }
    } else {
#pragma unroll
        for (int hA = 0; hA < 2; ++hA)
#pragma unroll
            for (int q = 0; q < 4; ++q)
#pragma unroll
                for (int hB = 0; hB < 2; ++hB)
#pragma unroll
                    for (int r = 0; r < 2; ++r)
#pragma unroll
                        for (int j = 0; j < 4; ++j) {
                            int row = m0 + hA * 128 + wr * 64 + q * 16 + lg * 4 + j;
                            int col = n0 + hB * 64 + wc * 32 + r * 16 + lr;
                            float v = acc[hA][q][hB][r][j];
                            if (MODE == 1) ((float*)Cp)[(size_t)row * N + col] = v;
                            else ((short*)Cp)[(size_t)row * N + col] = f2bf(v);
                        }
    }
#undef STG_A
#undef STG_B
}

// ---------------- fallback GEMM (round-1): f32 inputs, convert in-kernel ----------------
template <bool A_F32, bool C_F32>
__global__ __launch_bounds__(256)
void gemm_kernel(const void* __restrict__ Ap, const float* __restrict__ Bp,
                 void* __restrict__ Cp, int M, int N, int K) {
    const int BK = 32, PAD = 8, LDT = BK + PAD;
    __shared__ short As[128 * LDT];
    __shared__ short Bt[128 * LDT];
    const int tid = threadIdx.x;
    const int lane = tid & 63, w = tid >> 6;
    const int wr = w >> 1, wc = w & 1;
    const int lr = lane & 15, lg = lane >> 4;
    const int m0 = blockIdx.y * 128, n0 = blockIdx.x * 128;
    f32x4 acc[4][4] = {};

    for (int k0 = 0; k0 < K; k0 += BK) {
        __syncthreads();
        for (int it = 0; it < 4; ++it) {
            int row = (tid >> 3) + it * 32;
            int kk = (tid & 7) * 4;
            short4 o;
            if (A_F32) {
                const float* A = (const float*)Ap;
                float4 t = *(const float4*)&A[(size_t)(m0 + row) * K + k0 + kk];
                o.x = f2bf(t.x); o.y = f2bf(t.y); o.z = f2bf(t.z); o.w = f2bf(t.w);
            } else {
                const short* A = (const short*)Ap;
                o = *(const short4*)&A[(size_t)(m0 + row) * K + k0 + kk];
            }
            *(short4*)&As[row * LDT + kk] = o;
        }
        for (int it = 0; it < 4; ++it) {
            int krow = (tid >> 5) + it * 8;
            int col = (tid & 31) * 4;
            float4 t = *(const float4*)&Bp[(size_t)(k0 + krow) * N + n0 + col];
            Bt[(col + 0) * LDT + krow] = f2bf(t.x);
            Bt[(col + 1) * LDT + krow] = f2bf(t.y);
            Bt[(col + 2) * LDT + krow] = f2bf(t.z);
            Bt[(col + 3) * LDT + krow] = f2bf(t.w);
        }
        __syncthreads();
        bf16x8 af[4], bfr[4];
        for (int rb = 0; rb < 4; ++rb)
            af[rb] = *(const bf16x8*)&As[(wr * 64 + rb * 16 + lr) * LDT + lg * 8];
        for (int cb = 0; cb < 4; ++cb)
            bfr[cb] = *(const bf16x8*)&Bt[(wc * 64 + cb * 16 + lr) * LDT + lg * 8];
        for (int rb = 0; rb < 4; ++rb)
            for (int cb = 0; cb < 4; ++cb)
                acc[rb][cb] = __builtin_amdgcn_mfma_f32_16x16x32_bf16(
                    af[rb], bfr[cb], acc[rb][cb], 0, 0, 0);
    }

    for (int rb = 0; rb < 4; ++rb)
        for (int cb = 0; cb < 4; ++cb)
            for (int j = 0; j < 4; ++j) {
                int row = m0 + wr * 64 + rb * 16 + lg * 4 + j;
                int col = n0 + wc * 64 + cb * 16 + lr;
                float v = acc[rb][cb][j];
                if (C_F32) ((float*)Cp)[(size_t)row * N + col] = v;
                else ((short*)Cp)[(size_t)row * N + col] = f2bf(v);
            }
}

// ------- RoPE in-place (fallback path only); K pre-scaled log2(e)/sqrt(hd) -------
__global__ __launch_bounds__(256)
void rope_kernel(short* __restrict__ Qp, int ldq, short* __restrict__ Kp, int ldk) {
    const int QP = BATCH * SEQ * NHEADS * 64;
    const int KP = BATCH * SEQ * NKV * 64;
    const int total = QP + KP;
    const float kscale = 0.12751744695179782f;
    for (int idx = blockIdx.x * blockDim.x + threadIdx.x; idx < total;
         idx += gridDim.x * blockDim.x) {
        short* base;
        size_t off;
        int i, row;
        float scl;
        if (idx < QP) {
            i = idx & 63;
            int hh = (idx >> 6) & (NHEADS - 1);
            row = idx >> 10;
            base = Qp;
            off = (size_t)row * ldq + hh * HD;
            scl = 1.0f;
        } else {
            int t = idx - QP;
            i = t & 63;
            int hh = (t >> 6) & (NKV - 1);
            row = t >> 8;
            base = Kp;
            off = (size_t)row * ldk + hh * HD;
            scl = kscale;
        }
        int pos = row & (SEQ - 1);
        float invf = exp2f(-(float)i * (13.287712379549449f / 64.0f));
        float ang = (float)pos * invf;
        float s, c;
        sincosf(ang, &s, &c);
        float t1 = bf2f(base[off + i]);
        float t2 = bf2f(base[off + i + 64]);
        base[off + i] = f2bf((t1 * c - t2 * s) * scl);
        base[off + i + 64] = f2bf((t2 * c + t1 * s) * scl);
    }
}

// ---- Flash attention: 8 waves, QBLK=256, 32x32 MFMA, in-register P ----
// (R16 structure; packed f32x2 softmax trees; parked at ~144 us.
//  Falsified levers: LDS-read reduction, deep staging, packed softmax,
//  single-barrier, dual-QK intra-tile, T15 cross-tile (VGPR spills),
//  occupancy raises (reg spills). Chain-bound at this decomposition.)
__global__ __launch_bounds__(512, 2)
void attn_kernel(const short* __restrict__ Qp, int ldq,
                 const short* __restrict__ Kp, int ldk,
                 const short* __restrict__ Vp, int ldv,
                 short* __restrict__ O) {
    __shared__ short Ks[3][64 * 128];
    __shared__ short Vt[2][128 * 64];

    const int tid = threadIdx.x, lane = tid & 63, w = tid >> 6;
    const int l31 = lane & 31, lh = lane >> 5, l7 = lane & 7;
    const int hq = blockIdx.y, b = blockIdx.z;
    const int kvh = hq >> 2;
    const size_t brow = (size_t)b * SEQ;

    const int d0 = (tid & 15) * 8;
    const int rvb = (tid >> 4) * 2;   // 0..62 even
    bf16x8 vreg[2];

#define STAGE_K(T, BUF)                                                              \
    {                                                                                \
        _Pragma("unroll") for (int it = 0; it < 2; ++it) {                           \
            int row = w * 8 + it * 4 + (lane >> 4);                                  \
            int cblk = (lane & 15) ^ (row & 7);                                      \
            gload16(&Kp[(brow + (size_t)(T) * 64 + row) * ldk + kvh * HD + cblk * 8],\
                    &Ks[BUF][(w * 8 + it * 4) * 128]);                               \
        }                                                                            \
    }
#define LOAD_V(T)                                                                    \
    {                                                                                \
        _Pragma("unroll") for (int h2 = 0; h2 < 2; ++h2)                             \
            vreg[h2] = *(const bf16x8*)&Vp[(brow + (size_t)(T) * 64 + rvb + h2) *    \
                                           ldv + kvh * HD + d0];                     \
    }
#define WRITE_V(BUF)                                                                 \
    {                                                                                \
        _Pragma("unroll") for (int e = 0; e < 8; ++e) {                              \
            int dd = d0 + e;                                                         \
            int gg = (e ^ (tid & 15)) & 7;                                           \
            unsigned int pk = ((unsigned int)(unsigned short)vreg[0][e]) |           \
                              (((unsigned int)(unsigned short)vreg[1][e]) << 16);    \
            *(unsigned int*)&Vt[BUF][dd * 64 + (((rvb >> 3) ^ gg) << 3) + (rvb & 7)] = pk;\
        }                                                                            \
    }

    for (int pass = 0; pass < 2; ++pass) {
        const int qt = (pass == 0) ? (int)blockIdx.x : 7 - (int)blockIdx.x;
        const int q0 = qt * 256;
        const int qrow = q0 + w * 32 + l31;

        bf16x8 qf[8];
#pragma unroll
        for (int kc = 0; kc < 8; ++kc)
            qf[kc] = *(const bf16x8*)&Qp[(brow + qrow) * ldq + hq * HD +
                                         kc * 16 + lh * 8];

        f32x16 oacc[4] = {};
        float mrun = -__builtin_inff(), lrun = 0.f;

        const int ntiles = 4 * qt + 4;  // >= 4, even

        __syncthreads();
        STAGE_K(0, 0);
        LOAD_V(0);
        __syncthreads();
        WRITE_V(0);
        STAGE_K(1, 1);
        LOAD_V(1);
        __syncthreads();

        int cur = 0;
        int kcur = 0;
        for (int t = 0; t < ntiles; ++t) {
            const int nxt = cur ^ 1;
            const bool pre = (t + 1 < ntiles);
            const bool deep = (t + 2 < ntiles);
            const int kb2 = (kcur >= 1) ? kcur - 1 : kcur + 2;

            if (deep) { STAGE_K(t + 2, kb2); }

            f32x16 sacc[2] = {};
            __builtin_amdgcn_s_setprio(1);
#pragma unroll
            for (int kvb = 0; kvb < 2; ++kvb) {
                const int kvrow = kvb * 32 + l31;
#pragma unroll
                for (int kc = 0; kc < 8; ++kc) {
                    int c = kc * 2 + lh;
                    int cp = (c & 8) | ((c ^ l7) & 7);
                    bf16x8 kf = *(const bf16x8*)&Ks[kcur][kvrow * 128 + cp * 8];
                    sacc[kvb] = __builtin_amdgcn_mfma_f32_32x32x16_bf16(
                        kf, qf[kc], sacc[kvb], 0, 0, 0);
                }
            }
            __builtin_amdgcn_s_setprio(0);

            const int kv0 = t * 64;
            float st[32];
            const bool need_mask = (kv0 + 63 > qrow);
#pragma unroll
            for (int kvb = 0; kvb < 2; ++kvb)
#pragma unroll
                for (int r = 0; r < 16; ++r) {
                    float s = sacc[kvb][r];
                    if (need_mask) {
                        int kvloc = kvb * 32 + (r & 3) + 8 * (r >> 2) + 4 * lh;
                        if (kv0 + kvloc > qrow) s = -__builtin_inff();
                    }
                    st[kvb * 16 + r] = s;
                }

            // ---- packed-pair trees (f32x2) ----
            f32x2 p2[16];
#pragma unroll
            for (int i = 0; i < 16; ++i) p2[i] = (f32x2){st[2 * i], st[2 * i + 1]};

            f32x2 x8[8], x4[4], x2v[2], x1;
#pragma unroll
            for (int i = 0; i < 8; ++i) x8[i] = __builtin_elementwise_max(p2[i], p2[i + 8]);
#pragma unroll
            for (int i = 0; i < 4; ++i) x4[i] = __builtin_elementwise_max(x8[i], x8[i + 4]);
            x2v[0] = __builtin_elementwise_max(x4[0], x4[2]);
            x2v[1] = __builtin_elementwise_max(x4[1], x4[3]);
            x1 = __builtin_elementwise_max(x2v[0], x2v[1]);
            float rowmax = fmaxf(x1[0], x1[1]);
            rowmax = fmaxf(rowmax, __shfl_xor(rowmax, 32, 64));

            // defer-max (T13), log2 domain: 8 nats = 11.54 bits
            if (!__all(rowmax <= mrun + 11.54f)) {
                float mnew = fmaxf(mrun, rowmax);
                float alpha = fexp2(mrun - mnew);
                lrun *= alpha;
#pragma unroll
                for (int db = 0; db < 4; ++db)
#pragma unroll
                    for (int r = 0; r < 16; ++r) oacc[db][r] *= alpha;
                mrun = mnew;
            }
            const f32x2 mr2 = (f32x2){mrun, mrun};
#pragma unroll
            for (int i = 0; i < 16; ++i) {
                f32x2 d = p2[i] - mr2;
                st[2 * i] = fexp2(d[0]);
                st[2 * i + 1] = fexp2(d[1]);
            }
            f32x2 q2[16];
#pragma unroll
            for (int i = 0; i < 16; ++i) q2[i] = (f32x2){st[2 * i], st[2 * i + 1]};
            f32x2 t8[8], t4[4], t2v[2], t1;
#pragma unroll
            for (int i = 0; i < 8; ++i) t8[i] = q2[i] + q2[i + 8];
#pragma unroll
            for (int i = 0; i < 4; ++i) t4[i] = t8[i] + t8[i + 4];
            t2v[0] = t4[0] + t4[2];
            t2v[1] = t4[1] + t4[3];
            t1 = t2v[0] + t2v[1];
            float rs = t1[0] + t1[1];
            rs += __shfl_xor(rs, 32, 64);
            lrun += rs;

            if (pre) {
                WRITE_V(nxt);
                if (deep) { LOAD_V(t + 2); }
            }

            u32x4 pfrag[4];
#pragma unroll
            for (int kvc = 0; kvc < 4; ++kvc) {
                int base2 = (kvc >> 1) * 16 + (kvc & 1) * 8;
                unsigned int lo0 = cvtpk_bf16(st[base2 + 0], st[base2 + 1]);
                unsigned int lo1 = cvtpk_bf16(st[base2 + 2], st[base2 + 3]);
                unsigned int hi0 = cvtpk_bf16(st[base2 + 4], st[base2 + 5]);
                unsigned int hi1 = cvtpk_bf16(st[base2 + 6], st[base2 + 7]);
                unsigned int rlo0 = __shfl_xor(lo0, 32, 64);
                unsigned int rlo1 = __shfl_xor(lo1, 32, 64);
                unsigned int rhi0 = __shfl_xor(hi0, 32, 64);
                unsigned int rhi1 = __shfl_xor(hi1, 32, 64);
                u32x4 pu;
                pu[0] = lh ? rhi0 : lo0;
                pu[1] = lh ? rhi1 : lo1;
                pu[2] = lh ? hi0 : rlo0;
                pu[3] = lh ? hi1 : rlo1;
                pfrag[kvc] = pu;
            }

            __builtin_amdgcn_s_setprio(1);
#pragma unroll
            for (int db = 0; db < 4; ++db) {
                const int d = db * 32 + l31;
                const int g = (d ^ (d >> 3)) & 7;
#pragma unroll
                for (int kvc = 0; kvc < 4; ++kvc) {
                    int cp = ((kvc * 2 + lh) ^ g) & 7;
                    bf16x8 vf = *(const bf16x8*)&Vt[cur][d * 64 + cp * 8];
                    oacc[db] = __builtin_amdgcn_mfma_f32_32x32x16_bf16(
                        vf, __builtin_bit_cast(bf16x8, pfrag[kvc]), oacc[db], 0, 0, 0);
                }
            }
            __builtin_amdgcn_s_setprio(0);

            if (pre) {
                if (deep) { wbar6lg(); } else { wbar0lg(); }
                cur = nxt;
                kcur = (kcur < 2) ? kcur + 1 : 0;
            }
        }

        const float invl = 1.0f / lrun;
#pragma unroll
        for (int db = 0; db < 4; ++db)
#pragma unroll
            for (int j = 0; j < 4; ++j) {
                short4 o4;
                o4.x = f2bf(oacc[db][j * 4 + 0] * invl);
                o4.y = f2bf(oacc[db][j * 4 + 1] * invl);
                o4.z = f2bf(oacc[db][j * 4 + 2] * invl);
                o4.w = f2bf(oacc[db][j * 4 + 3] * invl);
                *(short4*)&O[(brow + qrow) * DMODEL + hq * HD +
                             db * 32 + 8 * j + 4 * lh] = o4;
            }
    }
#undef STAGE_K
#undef LOAD_V
#undef WRITE_V
}

extern "C" void kernel_launch(void* const* d_in, const int* in_sizes, int n_in,
                              void* d_out, int out_size, void* d_ws, size_t ws_size,
                              hipStream_t stream) {
    const float* x = (const float*)d_in[0];
    const float* Wq = (const float*)d_in[1];
    const float* Wk = (const float*)d_in[2];
    const float* Wv = (const float*)d_in[3];
    const float* Wo = (const float*)d_in[4];
    float* out = (float*)d_out;

    const size_t BS = (size_t)BATCH * SEQ;  // 8192
    dim3 blk(256);

    const size_t planA_shorts = BS * 2048 + BS * 3072 + (size_t)3072 * 2048 + (size_t)2048 * 2048;
    if (ws_size >= planA_shorts * 2) {
        short* xb = (short*)d_ws;                    // [8192][2048] bf16 (reused as AO)
        short* QKV = xb + BS * 2048;                 // [8192][3072]: Q | K | V
        short* WqkvT = QKV + BS * 3072;              // [3072][2048]
        short* WoT = WqkvT + (size_t)3072 * 2048;    // [2048][2048]
        short* AO = xb;

        prep<<<dim3(4608), blk, 0, stream>>>(x, xb, Wq, Wk, Wv, Wo, WqkvT, WoT);
        gemm_sb<2><<<dim3(768), blk, 0, stream>>>(xb, WqkvT, (void*)QKV,
                                                  8192, 3072, 2048, 24);
        attn_kernel<<<dim3(4, NHEADS, BATCH), dim3(512), 0, stream>>>(
            QKV, 3072, QKV + 2048, 3072, QKV + 2560, 3072, AO);
        gemm_sb<1><<<dim3(512), blk, 0, stream>>>(AO, WoT, (void*)out,
                                                  8192, 2048, 2048, 16);
    } else {
        short* Qb = (short*)d_ws;
        short* Kb = Qb + BS * DMODEL;
        short* Vb = Kb + BS * (NKV * HD);
        short* AO = Vb + BS * (NKV * HD);
        gemm_kernel<true, false><<<dim3(16, 64), blk, 0, stream>>>((const void*)x, Wq, (void*)Qb, 8192, 2048, 2048);
        gemm_kernel<true, false><<<dim3(4, 64), blk, 0, stream>>>((const void*)x, Wk, (void*)Kb, 8192, 512, 2048);
        gemm_kernel<true, false><<<dim3(4, 64), blk, 0, stream>>>((const void*)x, Wv, (void*)Vb, 8192, 512, 2048);
        rope_kernel<<<dim3(4096), blk, 0, stream>>>(Qb, 2048, Kb, 512);
        attn_kernel<<<dim3(4, NHEADS, BATCH), dim3(512), 0, stream>>>(
            Qb, 2048, Kb, 512, Vb, 512, AO);
        gemm_kernel<false, true><<<dim3(16, 64), blk, 0, stream>>>((const void*)AO, Wo, (void*)out, 8192, 2048, 2048);
    }
}